// Round 5
// baseline (321.125 us; speedup 1.0000x reference)
//
#include <hip/hip_runtime.h>

// FP8 MLP, fully fused:  out = q(relu(q(x)@q(w1)^T)) @ q(w2)^T
// R5: R4 skeleton (32x32x16 MFMA, 64x64 wave tiles, M=128, chunk=512, 16-wave
// blocks, grid=256) with: (1) correct slot involution g^((row>>1)&3) on stage
// source + frag reads (8 lanes/bank-quad uniform), (2) cross-iteration register
// prefetch of p-half frags + setprio around MFMA clusters (anti-convoy),
// (3) fc2 w2 loads hoisted to chunk top.

typedef float f32x4 __attribute__((ext_vector_type(4)));
typedef float f32x16 __attribute__((ext_vector_type(16)));

#define DIN 784
#define KP  832          // 13 * 64 (zero-padded K)
#define DH  4096
#define NKS 13
#define NCH 8
#define CHUNK 512
#define MROWS 128

__device__ __forceinline__ void gload_lds16(const void* g, void* l) {
  __builtin_amdgcn_global_load_lds(
      (const __attribute__((address_space(1))) unsigned int*)g,
      (__attribute__((address_space(3))) unsigned int*)l, 16, 0, 0);
}

__device__ __forceinline__ unsigned long long q8(float4 a, float4 b) {
  int lo = __builtin_amdgcn_cvt_pk_fp8_f32(a.x, a.y, 0, false);
  lo     = __builtin_amdgcn_cvt_pk_fp8_f32(a.z, a.w, lo, true);
  int hi = __builtin_amdgcn_cvt_pk_fp8_f32(b.x, b.y, 0, false);
  hi     = __builtin_amdgcn_cvt_pk_fp8_f32(b.z, b.w, hi, true);
  return (unsigned long long)(unsigned)lo |
         ((unsigned long long)(unsigned)hi << 32);
}

// ---- quantize row-major f32 [rows][784] -> fp8 [rows][KP], k-interleaved ----
// Row byte p = ks*64 + hi*32 + kk*8 + j  holds  q(src[row][ks*64 + kk*16 + hi*8 + j]).

__global__ __launch_bounds__(256) void quant_in_k(const float* __restrict__ src,
                                                  unsigned char* __restrict__ dst) {
  int idx = blockIdx.x * 256 + threadIdx.x;     // rows * 52 threads (exact)
  int row = idx / 52, g = idx % 52;
  int ks = g >> 2, q = g & 3;
  int k0 = ks * 64 + (q & 1) * 32 + (q >> 1) * 8;
  int k1 = k0 + 16;
  const float* r = src + (size_t)row * DIN;
  unsigned long long va = 0ull, vb = 0ull;
  if (k0 < DIN) va = q8(*(const float4*)(r + k0), *(const float4*)(r + k0 + 4));
  if (k1 < DIN) vb = q8(*(const float4*)(r + k1), *(const float4*)(r + k1 + 4));
  ulonglong2 v; v.x = va; v.y = vb;
  *(ulonglong2*)(dst + (size_t)row * KP + ks * 64 + q * 16) = v;
}

__global__ __launch_bounds__(256) void quant_w2_k(const float* __restrict__ w2,
                                                  unsigned char* __restrict__ w2q) {
  int idx = blockIdx.x * 256 + threadIdx.x;     // 16 rows * 256 chunks(16B)
  int r = idx >> 8, c = idx & 255;
  ulonglong2 v; v.x = 0ull; v.y = 0ull;
  if (r < 10) {
    const float* p = w2 + (size_t)r * DH + c * 16;
    v.x = q8(*(const float4*)(p), *(const float4*)(p + 4));
    v.y = q8(*(const float4*)(p + 8), *(const float4*)(p + 12));
  }
  *(ulonglong2*)(w2q + (size_t)r * DH + c * 16) = v;  // rows 10..15 = 0
}

// ------------------------------ fused MLP -----------------------------------

__global__ __launch_bounds__(1024, 4)
void fused_mlp(const unsigned char* __restrict__ xq,
               const unsigned char* __restrict__ w1q,
               const unsigned char* __restrict__ w2q,
               float* __restrict__ out) {
  __shared__ unsigned char Bt[2][CHUNK * 64];   // 64 KB
  __shared__ unsigned char Xt[2][MROWS * 64];   // 16 KB
  __shared__ unsigned char H[MROWS * CHUNK];    // 64 KB

  const int tid = threadIdx.x;
  const int lane = tid & 63;
  const int w  = tid >> 6;          // wave 0..15
  const int l31 = lane & 31;
  const int hi  = lane >> 5;
  const int wbi = w & 1, wdi = w >> 1;   // fc1 tile: batch 64-half, dh 64-slice
  const int fr  = w >> 1, kh = w & 1;    // fc2: row-frag, k-half
  const long row0 = (long)blockIdx.x * MROWS;

#define STAGE(nch_, ks_, b_)                                                   \
  do {                                                                         \
    { int i_ = tid, n_ = i_ >> 2, s_ = i_ & 3, g_ = s_ ^ ((n_ >> 1) & 3);      \
      gload_lds16(w1q + (size_t)((nch_)*CHUNK + n_) * KP + (ks_)*64 + g_*16,   \
                  &Bt[b_][i_ * 16]); }                                         \
    { int i_ = tid + 1024, n_ = i_ >> 2, s_ = i_ & 3, g_ = s_ ^ ((n_ >> 1) & 3);\
      gload_lds16(w1q + (size_t)((nch_)*CHUNK + n_) * KP + (ks_)*64 + g_*16,   \
                  &Bt[b_][i_ * 16]); }                                         \
    if (w < 8) {                                                               \
      int n_ = tid >> 2, s_ = tid & 3, g_ = s_ ^ ((n_ >> 1) & 3);              \
      gload_lds16(xq + (row0 + n_) * KP + (ks_)*64 + g_*16,                    \
                  &Xt[b_][tid * 16]); }                                        \
  } while (0)

  const int ar0 = wdi * 64 + l31, ar1 = ar0 + 32;   // w1 rows (dh)
  const int br0 = wbi * 64 + l31, br1 = br0 + 32;   // x rows (batch)
  // LDS byte offsets: off(row, g) = row*64 + (g ^ ((row>>1)&3))*16
  const int pA0 = ar0 * 64 + (((hi * 2 + 0) ^ ((ar0 >> 1) & 3)) << 4);
  const int qA0 = ar0 * 64 + (((hi * 2 + 1) ^ ((ar0 >> 1) & 3)) << 4);
  const int pA1 = ar1 * 64 + (((hi * 2 + 0) ^ ((ar1 >> 1) & 3)) << 4);
  const int qA1 = ar1 * 64 + (((hi * 2 + 1) ^ ((ar1 >> 1) & 3)) << 4);
  const int pB0 = br0 * 64 + (((hi * 2 + 0) ^ ((br0 >> 1) & 3)) << 4);
  const int qB0 = br0 * 64 + (((hi * 2 + 1) ^ ((br0 >> 1) & 3)) << 4);
  const int pB1 = br1 * 64 + (((hi * 2 + 0) ^ ((br1 >> 1) & 3)) << 4);
  const int qB1 = br1 * 64 + (((hi * 2 + 1) ^ ((br1 >> 1) & 3)) << 4);

  STAGE(0, 0, 0);
  asm volatile("s_waitcnt vmcnt(0)" ::: "memory");
  __syncthreads();

  // p-half register prefetch of tile 0
  ulonglong2 a0p = *(const ulonglong2*)&Bt[0][pA0];
  ulonglong2 a1p = *(const ulonglong2*)&Bt[0][pA1];
  ulonglong2 b0p = *(const ulonglong2*)&Xt[0][pB0];
  ulonglong2 b1p = *(const ulonglong2*)&Xt[0][pB1];

  f32x4 acc2 = {0.f, 0.f, 0.f, 0.f};
  int buf = 0;
  for (int nch = 0; nch < NCH; ++nch) {
    // hoist fc2 weights for this chunk (consumed at ks == NKS-1)
    long b2v[8];
    {
      const unsigned char* w2p =
          w2q + (size_t)(lane & 15) * DH + nch * CHUNK + kh * 256 + (lane >> 4) * 8;
#pragma unroll
      for (int kk = 0; kk < 8; ++kk) b2v[kk] = *(const long long*)(w2p + kk * 32);
    }
    f32x16 acc00 = {}, acc01 = {}, acc10 = {}, acc11 = {};
#pragma unroll 1
    for (int ks = 0; ks < NKS; ++ks) {
      if (ks < NKS - 1)       STAGE(nch, ks + 1, buf ^ 1);
      else if (nch < NCH - 1) STAGE(nch + 1, 0, buf ^ 1);

      // q-half reads (overlap p-MFMAs below)
      ulonglong2 a0q = *(const ulonglong2*)&Bt[buf][qA0];
      ulonglong2 a1q = *(const ulonglong2*)&Bt[buf][qA1];
      ulonglong2 b0q = *(const ulonglong2*)&Xt[buf][qB0];
      ulonglong2 b1q = *(const ulonglong2*)&Xt[buf][qB1];

      __builtin_amdgcn_s_setprio(1);
      acc00 = __builtin_amdgcn_mfma_f32_32x32x16_fp8_fp8((long)a0p.x, (long)b0p.x, acc00, 0, 0, 0);
      acc01 = __builtin_amdgcn_mfma_f32_32x32x16_fp8_fp8((long)a0p.x, (long)b1p.x, acc01, 0, 0, 0);
      acc10 = __builtin_amdgcn_mfma_f32_32x32x16_fp8_fp8((long)a1p.x, (long)b0p.x, acc10, 0, 0, 0);
      acc11 = __builtin_amdgcn_mfma_f32_32x32x16_fp8_fp8((long)a1p.x, (long)b1p.x, acc11, 0, 0, 0);
      acc00 = __builtin_amdgcn_mfma_f32_32x32x16_fp8_fp8((long)a0p.y, (long)b0p.y, acc00, 0, 0, 0);
      acc01 = __builtin_amdgcn_mfma_f32_32x32x16_fp8_fp8((long)a0p.y, (long)b1p.y, acc01, 0, 0, 0);
      acc10 = __builtin_amdgcn_mfma_f32_32x32x16_fp8_fp8((long)a1p.y, (long)b0p.y, acc10, 0, 0, 0);
      acc11 = __builtin_amdgcn_mfma_f32_32x32x16_fp8_fp8((long)a1p.y, (long)b1p.y, acc11, 0, 0, 0);
      __builtin_amdgcn_s_setprio(0);

      __builtin_amdgcn_s_setprio(1);
      acc00 = __builtin_amdgcn_mfma_f32_32x32x16_fp8_fp8((long)a0q.x, (long)b0q.x, acc00, 0, 0, 0);
      acc01 = __builtin_amdgcn_mfma_f32_32x32x16_fp8_fp8((long)a0q.x, (long)b1q.x, acc01, 0, 0, 0);
      acc10 = __builtin_amdgcn_mfma_f32_32x32x16_fp8_fp8((long)a1q.x, (long)b0q.x, acc10, 0, 0, 0);
      acc11 = __builtin_amdgcn_mfma_f32_32x32x16_fp8_fp8((long)a1q.x, (long)b1q.x, acc11, 0, 0, 0);
      acc00 = __builtin_amdgcn_mfma_f32_32x32x16_fp8_fp8((long)a0q.y, (long)b0q.y, acc00, 0, 0, 0);
      acc01 = __builtin_amdgcn_mfma_f32_32x32x16_fp8_fp8((long)a0q.y, (long)b1q.y, acc01, 0, 0, 0);
      acc10 = __builtin_amdgcn_mfma_f32_32x32x16_fp8_fp8((long)a1q.y, (long)b0q.y, acc10, 0, 0, 0);
      acc11 = __builtin_amdgcn_mfma_f32_32x32x16_fp8_fp8((long)a1q.y, (long)b1q.y, acc11, 0, 0, 0);
      __builtin_amdgcn_s_setprio(0);

      if (ks == NKS - 1) {
        // ---- relu + quantize -> H. D(32x32): col(batch)=l31,
        //      dh-in-frag = (reg&3) + 8*(reg>>2) + 4*hi ----
        const int dh00 = wdi * 64 + 4 * hi;
        const int dh10 = dh00 + 32;
#define HWR(accv, rbv, dhb)                                                    \
        do {                                                                   \
          _Pragma("unroll") for (int qq = 0; qq < 4; ++qq) {                   \
            int dh_ = (dhb) + 8 * qq;                                          \
            unsigned wv = (unsigned)__builtin_amdgcn_cvt_pk_fp8_f32(           \
                fmaxf((accv)[4*qq+0], 0.f), fmaxf((accv)[4*qq+1], 0.f), 0, false); \
            wv = (unsigned)__builtin_amdgcn_cvt_pk_fp8_f32(                    \
                fmaxf((accv)[4*qq+2], 0.f), fmaxf((accv)[4*qq+3], 0.f), (int)wv, true); \
            int sp_ = (dh_ >> 2) ^ (((rbv) & 15) << 1);                        \
            *(unsigned int*)&H[(rbv) * CHUNK + sp_ * 4] = wv;                  \
          }                                                                    \
        } while (0)
        HWR(acc00, br0, dh00);
        HWR(acc01, br1, dh00);
        HWR(acc10, br0, dh10);
        HWR(acc11, br1, dh10);
#undef HWR
        asm volatile("s_waitcnt lgkmcnt(0)" ::: "memory");
        __builtin_amdgcn_s_barrier();
        asm volatile("" ::: "memory");
        // ---- fc2: 8 MFMAs (16x16x32) over this chunk's k-half ----
        const int r2 = fr * 16 + (lane & 15);
        const int xsw = (r2 & 15) << 1;
#pragma unroll
        for (int kk = 0; kk < 8; ++kk) {
          int dhl = kh * 256 + kk * 32 + (lane >> 4) * 8;
          long a2 = *(const long long*)&H[r2 * CHUNK + (((dhl >> 2) ^ xsw) << 2)];
          acc2 = __builtin_amdgcn_mfma_f32_16x16x32_fp8_fp8(a2, b2v[kk], acc2, 0, 0, 0);
        }
      }

      asm volatile("s_waitcnt vmcnt(0)" ::: "memory");
      __builtin_amdgcn_s_barrier();
      asm volatile("" ::: "memory");
      buf ^= 1;

      // p-half register prefetch of the tile that just landed
      if (ks < NKS - 1 || nch < NCH - 1) {
        a0p = *(const ulonglong2*)&Bt[buf][pA0];
        a1p = *(const ulonglong2*)&Bt[buf][pA1];
        b0p = *(const ulonglong2*)&Xt[buf][pB0];
        b1p = *(const ulonglong2*)&Xt[buf][pB1];
      }
    }
  }

  // ---- pair-reduce fc2 k-halves (waves 2f and 2f+1), store out ----
  float* red = (float*)&Xt[0][0];
  if (kh == 1) {
#pragma unroll
    for (int j = 0; j < 4; ++j)
      red[(fr * 16 + (lane >> 4) * 4 + j) * 16 + (lane & 15)] = acc2[j];
  }
  __syncthreads();
  if (kh == 0 && (lane & 15) < 10) {
#pragma unroll
    for (int j = 0; j < 4; ++j) {
      int rl = fr * 16 + (lane >> 4) * 4 + j;
      out[(row0 + rl) * 10 + (lane & 15)] = acc2[j] + red[rl * 16 + (lane & 15)];
    }
  }
#undef STAGE
}

extern "C" void kernel_launch(void* const* d_in, const int* in_sizes, int n_in,
                              void* d_out, int out_size, void* d_ws, size_t ws_size,
                              hipStream_t stream) {
  const float* x  = (const float*)d_in[0];
  const float* w1 = (const float*)d_in[1];
  const float* w2 = (const float*)d_in[2];
  float* out = (float*)d_out;

  unsigned char* w1q = (unsigned char*)d_ws;              // [4096][832]
  unsigned char* w2q = w1q + (size_t)DH * KP;             // [16][4096]
  unsigned char* xq  = w2q + (size_t)16 * DH;             // [32768][832]

  quant_in_k<<<(DH * 52) / 256, 256, 0, stream>>>(w1, w1q);
  quant_w2_k<<<16, 256, 0, stream>>>(w2, w2q);
  quant_in_k<<<(32768 * 52) / 256, 256, 0, stream>>>(x, xq);
  fused_mlp<<<256, 1024, 0, stream>>>(xq, w1q, w2q, out);
}

// Round 6
// 262.628 us; speedup vs baseline: 1.2227x; 1.2227x over previous
//
#include <hip/hip_runtime.h>

// FP8 MLP, fully fused:  out = q(relu(q(x)@q(w1)^T)) @ q(w2)^T
// R6: R4 skeleton (32x32x16 MFMA, 64x64 wave tiles, M=128, chunk=512, 16-wave
// blocks, grid=256) + R5's correct slot involution g^((row>>1)&3).
// Register discipline: NO cross-iteration prefetch, NO w2 hoist (R5's spills:
// WRITE_SIZE 203MB). K-step split into two sched_barrier(0)-walled phases of
// {4 b128 reads -> 8 MFMAs} to cap live frag regs at 16 and interleave waves.

typedef float f32x4 __attribute__((ext_vector_type(4)));
typedef float f32x16 __attribute__((ext_vector_type(16)));

#define DIN 784
#define KP  832          // 13 * 64 (zero-padded K)
#define DH  4096
#define NKS 13
#define NCH 8
#define CHUNK 512
#define MROWS 128

__device__ __forceinline__ void gload_lds16(const void* g, void* l) {
  __builtin_amdgcn_global_load_lds(
      (const __attribute__((address_space(1))) unsigned int*)g,
      (__attribute__((address_space(3))) unsigned int*)l, 16, 0, 0);
}

__device__ __forceinline__ unsigned long long q8(float4 a, float4 b) {
  int lo = __builtin_amdgcn_cvt_pk_fp8_f32(a.x, a.y, 0, false);
  lo     = __builtin_amdgcn_cvt_pk_fp8_f32(a.z, a.w, lo, true);
  int hi = __builtin_amdgcn_cvt_pk_fp8_f32(b.x, b.y, 0, false);
  hi     = __builtin_amdgcn_cvt_pk_fp8_f32(b.z, b.w, hi, true);
  return (unsigned long long)(unsigned)lo |
         ((unsigned long long)(unsigned)hi << 32);
}

// ---- quantize row-major f32 [rows][784] -> fp8 [rows][KP], k-interleaved ----
// Row byte p = ks*64 + hi*32 + kk*8 + j  holds  q(src[row][ks*64 + kk*16 + hi*8 + j]).

__global__ __launch_bounds__(256) void quant_in_k(const float* __restrict__ src,
                                                  unsigned char* __restrict__ dst) {
  int idx = blockIdx.x * 256 + threadIdx.x;     // rows * 52 threads (exact)
  int row = idx / 52, g = idx % 52;
  int ks = g >> 2, q = g & 3;
  int k0 = ks * 64 + (q & 1) * 32 + (q >> 1) * 8;
  int k1 = k0 + 16;
  const float* r = src + (size_t)row * DIN;
  unsigned long long va = 0ull, vb = 0ull;
  if (k0 < DIN) va = q8(*(const float4*)(r + k0), *(const float4*)(r + k0 + 4));
  if (k1 < DIN) vb = q8(*(const float4*)(r + k1), *(const float4*)(r + k1 + 4));
  ulonglong2 v; v.x = va; v.y = vb;
  *(ulonglong2*)(dst + (size_t)row * KP + ks * 64 + q * 16) = v;
}

__global__ __launch_bounds__(256) void quant_w2_k(const float* __restrict__ w2,
                                                  unsigned char* __restrict__ w2q) {
  int idx = blockIdx.x * 256 + threadIdx.x;     // 16 rows * 256 chunks(16B)
  int r = idx >> 8, c = idx & 255;
  ulonglong2 v; v.x = 0ull; v.y = 0ull;
  if (r < 10) {
    const float* p = w2 + (size_t)r * DH + c * 16;
    v.x = q8(*(const float4*)(p), *(const float4*)(p + 4));
    v.y = q8(*(const float4*)(p + 8), *(const float4*)(p + 12));
  }
  *(ulonglong2*)(w2q + (size_t)r * DH + c * 16) = v;  // rows 10..15 = 0
}

// ------------------------------ fused MLP -----------------------------------

__global__ __launch_bounds__(1024, 4)
void fused_mlp(const unsigned char* __restrict__ xq,
               const unsigned char* __restrict__ w1q,
               const unsigned char* __restrict__ w2q,
               float* __restrict__ out) {
  __shared__ unsigned char Bt[2][CHUNK * 64];   // 64 KB
  __shared__ unsigned char Xt[2][MROWS * 64];   // 16 KB
  __shared__ unsigned char H[MROWS * CHUNK];    // 64 KB

  const int tid = threadIdx.x;
  const int lane = tid & 63;
  const int w  = tid >> 6;          // wave 0..15
  const int l31 = lane & 31;
  const int hi  = lane >> 5;
  const int wbi = w & 1, wdi = w >> 1;   // fc1 tile: batch 64-half, dh 64-slice
  const int fr  = w >> 1, kh = w & 1;    // fc2: row-frag, k-half
  const long row0 = (long)blockIdx.x * MROWS;

#define STAGE(nch_, ks_, b_)                                                   \
  do {                                                                         \
    { int i_ = tid, n_ = i_ >> 2, s_ = i_ & 3, g_ = s_ ^ ((n_ >> 1) & 3);      \
      gload_lds16(w1q + (size_t)((nch_)*CHUNK + n_) * KP + (ks_)*64 + g_*16,   \
                  &Bt[b_][i_ * 16]); }                                         \
    { int i_ = tid + 1024, n_ = i_ >> 2, s_ = i_ & 3, g_ = s_ ^ ((n_ >> 1) & 3);\
      gload_lds16(w1q + (size_t)((nch_)*CHUNK + n_) * KP + (ks_)*64 + g_*16,   \
                  &Bt[b_][i_ * 16]); }                                         \
    if (w < 8) {                                                               \
      int n_ = tid >> 2, s_ = tid & 3, g_ = s_ ^ ((n_ >> 1) & 3);              \
      gload_lds16(xq + (row0 + n_) * KP + (ks_)*64 + g_*16,                    \
                  &Xt[b_][tid * 16]); }                                        \
  } while (0)

  const int ar0 = wdi * 64 + l31, ar1 = ar0 + 32;   // w1 rows (dh)
  const int br0 = wbi * 64 + l31, br1 = br0 + 32;   // x rows (batch)
  // LDS byte offsets: off(row, g) = row*64 + (g ^ ((row>>1)&3))*16
  const int pA0 = ar0 * 64 + (((hi * 2 + 0) ^ ((ar0 >> 1) & 3)) << 4);
  const int qA0 = ar0 * 64 + (((hi * 2 + 1) ^ ((ar0 >> 1) & 3)) << 4);
  const int pA1 = ar1 * 64 + (((hi * 2 + 0) ^ ((ar1 >> 1) & 3)) << 4);
  const int qA1 = ar1 * 64 + (((hi * 2 + 1) ^ ((ar1 >> 1) & 3)) << 4);
  const int pB0 = br0 * 64 + (((hi * 2 + 0) ^ ((br0 >> 1) & 3)) << 4);
  const int qB0 = br0 * 64 + (((hi * 2 + 1) ^ ((br0 >> 1) & 3)) << 4);
  const int pB1 = br1 * 64 + (((hi * 2 + 0) ^ ((br1 >> 1) & 3)) << 4);
  const int qB1 = br1 * 64 + (((hi * 2 + 1) ^ ((br1 >> 1) & 3)) << 4);

  STAGE(0, 0, 0);
  asm volatile("s_waitcnt vmcnt(0)" ::: "memory");
  __syncthreads();

  f32x4 acc2 = {0.f, 0.f, 0.f, 0.f};
  int buf = 0;
  for (int nch = 0; nch < NCH; ++nch) {
    f32x16 acc00 = {}, acc01 = {}, acc10 = {}, acc11 = {};
#pragma unroll 1
    for (int ks = 0; ks < NKS; ++ks) {
      if (ks < NKS - 1)       STAGE(nch, ks + 1, buf ^ 1);
      else if (nch < NCH - 1) STAGE(nch + 1, 0, buf ^ 1);

      // ---- phase 1: p-half (4 b128 reads, 8 MFMAs) ----
      {
        ulonglong2 a0 = *(const ulonglong2*)&Bt[buf][pA0];
        ulonglong2 a1 = *(const ulonglong2*)&Bt[buf][pA1];
        ulonglong2 b0 = *(const ulonglong2*)&Xt[buf][pB0];
        ulonglong2 b1 = *(const ulonglong2*)&Xt[buf][pB1];
        __builtin_amdgcn_s_setprio(1);
        acc00 = __builtin_amdgcn_mfma_f32_32x32x16_fp8_fp8((long)a0.x, (long)b0.x, acc00, 0, 0, 0);
        acc01 = __builtin_amdgcn_mfma_f32_32x32x16_fp8_fp8((long)a0.x, (long)b1.x, acc01, 0, 0, 0);
        acc10 = __builtin_amdgcn_mfma_f32_32x32x16_fp8_fp8((long)a1.x, (long)b0.x, acc10, 0, 0, 0);
        acc11 = __builtin_amdgcn_mfma_f32_32x32x16_fp8_fp8((long)a1.x, (long)b1.x, acc11, 0, 0, 0);
        acc00 = __builtin_amdgcn_mfma_f32_32x32x16_fp8_fp8((long)a0.y, (long)b0.y, acc00, 0, 0, 0);
        acc01 = __builtin_amdgcn_mfma_f32_32x32x16_fp8_fp8((long)a0.y, (long)b1.y, acc01, 0, 0, 0);
        acc10 = __builtin_amdgcn_mfma_f32_32x32x16_fp8_fp8((long)a1.y, (long)b0.y, acc10, 0, 0, 0);
        acc11 = __builtin_amdgcn_mfma_f32_32x32x16_fp8_fp8((long)a1.y, (long)b1.y, acc11, 0, 0, 0);
        __builtin_amdgcn_s_setprio(0);
      }
      __builtin_amdgcn_sched_barrier(0);
      // ---- phase 2: q-half ----
      {
        ulonglong2 a0 = *(const ulonglong2*)&Bt[buf][qA0];
        ulonglong2 a1 = *(const ulonglong2*)&Bt[buf][qA1];
        ulonglong2 b0 = *(const ulonglong2*)&Xt[buf][qB0];
        ulonglong2 b1 = *(const ulonglong2*)&Xt[buf][qB1];
        __builtin_amdgcn_s_setprio(1);
        acc00 = __builtin_amdgcn_mfma_f32_32x32x16_fp8_fp8((long)a0.x, (long)b0.x, acc00, 0, 0, 0);
        acc01 = __builtin_amdgcn_mfma_f32_32x32x16_fp8_fp8((long)a0.x, (long)b1.x, acc01, 0, 0, 0);
        acc10 = __builtin_amdgcn_mfma_f32_32x32x16_fp8_fp8((long)a1.x, (long)b0.x, acc10, 0, 0, 0);
        acc11 = __builtin_amdgcn_mfma_f32_32x32x16_fp8_fp8((long)a1.x, (long)b1.x, acc11, 0, 0, 0);
        acc00 = __builtin_amdgcn_mfma_f32_32x32x16_fp8_fp8((long)a0.y, (long)b0.y, acc00, 0, 0, 0);
        acc01 = __builtin_amdgcn_mfma_f32_32x32x16_fp8_fp8((long)a0.y, (long)b1.y, acc01, 0, 0, 0);
        acc10 = __builtin_amdgcn_mfma_f32_32x32x16_fp8_fp8((long)a1.y, (long)b0.y, acc10, 0, 0, 0);
        acc11 = __builtin_amdgcn_mfma_f32_32x32x16_fp8_fp8((long)a1.y, (long)b1.y, acc11, 0, 0, 0);
        __builtin_amdgcn_s_setprio(0);
      }

      if (ks == NKS - 1) {
        // ---- relu + quantize -> H. D(32x32): col(batch)=l31,
        //      dh-in-frag = (reg&3) + 8*(reg>>2) + 4*hi ----
        const int dh00 = wdi * 64 + 4 * hi;
        const int dh10 = dh00 + 32;
#define HWR(accv, rbv, dhb)                                                    \
        do {                                                                   \
          _Pragma("unroll") for (int qq = 0; qq < 4; ++qq) {                   \
            int dh_ = (dhb) + 8 * qq;                                          \
            unsigned wv = (unsigned)__builtin_amdgcn_cvt_pk_fp8_f32(           \
                fmaxf((accv)[4*qq+0], 0.f), fmaxf((accv)[4*qq+1], 0.f), 0, false); \
            wv = (unsigned)__builtin_amdgcn_cvt_pk_fp8_f32(                    \
                fmaxf((accv)[4*qq+2], 0.f), fmaxf((accv)[4*qq+3], 0.f), (int)wv, true); \
            int sp_ = (dh_ >> 2) ^ (((rbv) & 15) << 1);                        \
            *(unsigned int*)&H[(rbv) * CHUNK + sp_ * 4] = wv;                  \
          }                                                                    \
        } while (0)
        HWR(acc00, br0, dh00);
        HWR(acc01, br1, dh00);
        HWR(acc10, br0, dh10);
        HWR(acc11, br1, dh10);
#undef HWR
        asm volatile("s_waitcnt lgkmcnt(0)" ::: "memory");
        __builtin_amdgcn_s_barrier();
        asm volatile("" ::: "memory");
        // ---- fc2: 8 MFMAs (16x16x32) over this chunk's k-half ----
        const int r2 = fr * 16 + (lane & 15);
        const int xsw = (r2 & 15) << 1;
#pragma unroll
        for (int kk = 0; kk < 8; ++kk) {
          int dhl = kh * 256 + kk * 32 + (lane >> 4) * 8;
          long a2 = *(const long long*)&H[r2 * CHUNK + (((dhl >> 2) ^ xsw) << 2)];
          long b2 = *(const long long*)(w2q + (size_t)(lane & 15) * DH + nch * CHUNK + dhl);
          acc2 = __builtin_amdgcn_mfma_f32_16x16x32_fp8_fp8(a2, b2, acc2, 0, 0, 0);
        }
      }

      asm volatile("s_waitcnt vmcnt(0)" ::: "memory");
      __builtin_amdgcn_s_barrier();
      asm volatile("" ::: "memory");
      buf ^= 1;
    }
  }

  // ---- pair-reduce fc2 k-halves (waves 2f and 2f+1), store out ----
  float* red = (float*)&Xt[0][0];
  if (kh == 1) {
#pragma unroll
    for (int j = 0; j < 4; ++j)
      red[(fr * 16 + (lane >> 4) * 4 + j) * 16 + (lane & 15)] = acc2[j];
  }
  __syncthreads();
  if (kh == 0 && (lane & 15) < 10) {
#pragma unroll
    for (int j = 0; j < 4; ++j) {
      int rl = fr * 16 + (lane >> 4) * 4 + j;
      out[(row0 + rl) * 10 + (lane & 15)] = acc2[j] + red[rl * 16 + (lane & 15)];
    }
  }
#undef STAGE
}

extern "C" void kernel_launch(void* const* d_in, const int* in_sizes, int n_in,
                              void* d_out, int out_size, void* d_ws, size_t ws_size,
                              hipStream_t stream) {
  const float* x  = (const float*)d_in[0];
  const float* w1 = (const float*)d_in[1];
  const float* w2 = (const float*)d_in[2];
  float* out = (float*)d_out;

  unsigned char* w1q = (unsigned char*)d_ws;              // [4096][832]
  unsigned char* w2q = w1q + (size_t)DH * KP;             // [16][4096]
  unsigned char* xq  = w2q + (size_t)16 * DH;             // [32768][832]

  quant_in_k<<<(DH * 52) / 256, 256, 0, stream>>>(w1, w1q);
  quant_w2_k<<<16, 256, 0, stream>>>(w2, w2q);
  quant_in_k<<<(32768 * 52) / 256, 256, 0, stream>>>(x, xq);
  fused_mlp<<<256, 1024, 0, stream>>>(xq, w1q, w2q, out);
}